// Round 4
// baseline (243.787 us; speedup 1.0000x reference)
//
#include <hip/hip_runtime.h>

// Fused rel-pos attention, barrier-free wave-private design. v3 fix:
// Q-staging is exactly 256 work items (2si x 8h x 16 float4) -> no r-loop
// (v3's r-loop read Q out of bounds at s0+3 and crashed).
// B=4, H=8, S=512, D=64, fp32 in/out.
// Block = (b, 2-row s-tile), 256 threads (4 waves). Grid = 4*256 = 1024.
// Wave w owns slice (si = w>>1, heads hg*4..hg*4+3, hg = w&1) through ALL
// phases -> score buffer Pb is wave-private -> single __syncthreads total.
// LDS: Qs fp32 [2][8][64] (4 KB) + Pb bf16 [2][512][12] (24 KB) = 28.7 KB.
// Pb stride 24 B: breaks pow2 bank patterns; [si][t][h] packs 8 heads ->
// phase D reads 4 heads' p in one 8B LDS read (broadcast across d-lanes).

__device__ __forceinline__ unsigned short f2bf(float x) {
  unsigned int u = __float_as_uint(x);
  u += 0x7fffu + ((u >> 16) & 1u);   // RNE
  return (unsigned short)(u >> 16);
}
__device__ __forceinline__ float bf2f(unsigned int s) {
  return __uint_as_float(s << 16);
}

__global__ __launch_bounds__(256, 4)
void attn_v4(const float* __restrict__ Q, const float* __restrict__ K,
             const float* __restrict__ V, const float* __restrict__ R,
             const int* __restrict__ Mk, float* __restrict__ ans,
             float* __restrict__ pout) {
  __shared__ __align__(16) float Qs[2][8][64];
  __shared__ __align__(16) unsigned short Pb[2][512][12];

  const int tid = threadIdx.x;
  const int b  = blockIdx.x >> 8;
  const int s0 = (blockIdx.x & 255) << 1;

  // ---------------- stage Q tile (only cross-wave phase) ----------------
  {
    const int qd4 = tid & 15;
    const int qh  = (tid >> 4) & 7;
    const int qsi = tid >> 7;            // 0..1
    *reinterpret_cast<float4*>(&Qs[qsi][qh][qd4 << 2]) =
        *reinterpret_cast<const float4*>(
            Q + ((size_t)((((b << 3) + qh) << 9) + s0 + qsi) << 6) + (qd4 << 2));
  }
  __syncthreads();

  const int lane = tid & 63;
  const int w    = tid >> 6;
  const int si   = w >> 1;   // s-row within tile
  const int hg   = w & 1;    // head half: h = hg*4 + hh

  const float* Rb = R + (((size_t)((b << 9) + s0 + si)) << 15);

  // ---------------- Phase B: scores -> Pb (bf16, scaled, unmasked) ------
  {
    const int dgrp = lane & 15;   // d-slice of 4: d0 = dgrp*4
    const int tl   = lane >> 4;   // 0..3: t row within 4-chunk
    const int d0   = dgrp << 2;
    const bool c0 = (dgrp & 1) != 0;
    const bool c1 = (dgrp & 2) != 0;

    float q[4][4];
#pragma unroll
    for (int hh = 0; hh < 4; ++hh) {
      const float4 a = *reinterpret_cast<const float4*>(&Qs[si][(hg << 2) + hh][d0]);
      q[hh][0] = a.x; q[hh][1] = a.y; q[hh][2] = a.z; q[hh][3] = a.w;
    }

    const float* Kb = K + ((size_t)b << 18);

    auto loadKR = [&](int tt, float (&kv)[4][4], float (&rv)[4]) {
      const float4 r4 = *reinterpret_cast<const float4*>(Rb + (tt << 6) + d0);
      rv[0] = r4.x; rv[1] = r4.y; rv[2] = r4.z; rv[3] = r4.w;
#pragma unroll
      for (int hh = 0; hh < 4; ++hh) {
        const float4 k4 = *reinterpret_cast<const float4*>(
            Kb + (((((hg << 2) + hh) << 9) + tt) << 6) + d0);
        kv[hh][0] = k4.x; kv[hh][1] = k4.y; kv[hh][2] = k4.z; kv[hh][3] = k4.w;
      }
    };

    auto computeB = [&](int tt, const float (&kv)[4][4], const float (&rv)[4]) {
      float s[4];
#pragma unroll
      for (int hh = 0; hh < 4; ++hh) {
        float a = 0.0f;
#pragma unroll
        for (int d = 0; d < 4; ++d) a += q[hh][d] * (kv[hh][d] + rv[d]);
        s[hh] = a;
      }
      // distributing butterfly over dgrp bits 0..1, plain reduce bits 2..3:
      // lane ends with full d-sum for hh = dgrp&3 (4 copies across dgrp>>2)
      float n0 = (c0 ? s[1] : s[0]) + __shfl_xor(c0 ? s[0] : s[1], 1);
      float n1 = (c0 ? s[3] : s[2]) + __shfl_xor(c0 ? s[2] : s[3], 1);
      float f  = (c1 ? n1 : n0) + __shfl_xor(c1 ? n0 : n1, 2);
      f += __shfl_xor(f, 4);
      f += __shfl_xor(f, 8);
      if (dgrp < 4)
        Pb[si][tt][(hg << 2) + dgrp] = f2bf(f * 0.125f);
    };

    float kA[4][4], rA[4], kB[4][4], rB[4];
    loadKR(tl, kA, rA);
    for (int tc = 0; tc < 128; tc += 2) {
      const int t0 = (tc << 2) + tl;
      loadKR(t0 + 4, kB, rB);
      computeB(t0, kA, rA);
      if (tc < 126) loadKR(t0 + 8, kA, rA);
      computeB(t0 + 4, kB, rB);
    }
  }

  // ------- Phase C: softmax rows (wave-private, NO barrier needed) ------
  {
    float bias[8];
#pragma unroll
    for (int k = 0; k < 8; ++k)
      bias[k] = Mk[(b << 9) + lane + (k << 6)] ? 0.0f : -1.0e9f;

#pragma unroll
    for (int rr = 0; rr < 4; ++rr) {
      const int h = (hg << 2) + rr;
      float v[8];
#pragma unroll
      for (int k = 0; k < 8; ++k)
        v[k] = bf2f((unsigned int)Pb[si][lane + (k << 6)][h]) + bias[k];

      float m = v[0];
#pragma unroll
      for (int k = 1; k < 8; ++k) m = fmaxf(m, v[k]);
      m = fmaxf(m, __shfl_xor(m, 1));
      m = fmaxf(m, __shfl_xor(m, 2));
      m = fmaxf(m, __shfl_xor(m, 4));
      m = fmaxf(m, __shfl_xor(m, 8));
      m = fmaxf(m, __shfl_xor(m, 16));
      m = fmaxf(m, __shfl_xor(m, 32));

      float e[8], ss = 0.0f;
#pragma unroll
      for (int k = 0; k < 8; ++k) { e[k] = __expf(v[k] - m); ss += e[k]; }
      ss += __shfl_xor(ss, 1);
      ss += __shfl_xor(ss, 2);
      ss += __shfl_xor(ss, 4);
      ss += __shfl_xor(ss, 8);
      ss += __shfl_xor(ss, 16);
      ss += __shfl_xor(ss, 32);
      const float inv = 1.0f / ss;

      float* po = pout + ((size_t)((((b << 3) + h) << 9) + s0 + si) << 9);
#pragma unroll
      for (int k = 0; k < 8; ++k) {
        const float p = e[k] * inv;
        po[lane + (k << 6)] = p;
        Pb[si][lane + (k << 6)][h] = f2bf(p);
      }
    }
  }

  // ------- Phase D: out = P @ (V + R) (wave-private, NO barrier) --------
  {
    const int d4 = lane & 15, tg = lane >> 4;
    const int dd = d4 << 2;
    const float* Vb = V + ((size_t)b << 18);

    float acc[4][4];
#pragma unroll
    for (int hh = 0; hh < 4; ++hh)
#pragma unroll
      for (int c = 0; c < 4; ++c) acc[hh][c] = 0.0f;

    auto loadD = [&](int tt, float4 (&v4)[4], float4& r4) {
      r4 = *reinterpret_cast<const float4*>(Rb + (tt << 6) + dd);
#pragma unroll
      for (int hh = 0; hh < 4; ++hh)
        v4[hh] = *reinterpret_cast<const float4*>(
            Vb + (((((hg << 2) + hh) << 9) + tt) << 6) + dd);
    };

    auto computeD = [&](int tt, const float4 (&v4)[4], const float4& r4) {
      const uint2 pw = *reinterpret_cast<const uint2*>(&Pb[si][tt][hg << 2]);
      float p[4];
      p[0] = bf2f(pw.x & 0xffffu);
      p[1] = bf2f(pw.x >> 16);
      p[2] = bf2f(pw.y & 0xffffu);
      p[3] = bf2f(pw.y >> 16);
#pragma unroll
      for (int hh = 0; hh < 4; ++hh) {
        acc[hh][0] += p[hh] * (v4[hh].x + r4.x);
        acc[hh][1] += p[hh] * (v4[hh].y + r4.y);
        acc[hh][2] += p[hh] * (v4[hh].z + r4.z);
        acc[hh][3] += p[hh] * (v4[hh].w + r4.w);
      }
    };

    float4 vA[4], rA4, vB[4], rB4;
    loadD(tg, vA, rA4);
    for (int i = 0; i < 128; i += 2) {
      const int t0 = (i << 2) + tg;
      loadD(t0 + 4, vB, rB4);
      computeD(t0, vA, rA4);
      if (i < 126) loadD(t0 + 8, vA, rA4);
      computeD(t0 + 4, vB, rB4);
    }

    // reduce across the 4 tg groups (lane bits 4,5)
#pragma unroll
    for (int hh = 0; hh < 4; ++hh)
#pragma unroll
      for (int c = 0; c < 4; ++c) {
        float x = acc[hh][c];
        x += __shfl_xor(x, 16);
        x += __shfl_xor(x, 32);
        acc[hh][c] = x;
      }

    if (tg == 0) {
#pragma unroll
      for (int hh = 0; hh < 4; ++hh) {
        float4 o;
        o.x = acc[hh][0]; o.y = acc[hh][1]; o.z = acc[hh][2]; o.w = acc[hh][3];
        *reinterpret_cast<float4*>(
            ans + ((size_t)((((b << 3) + (hg << 2) + hh) << 9) + s0 + si) << 6) + dd) = o;
      }
    }
  }
}

extern "C" void kernel_launch(void* const* d_in, const int* in_sizes, int n_in,
                              void* d_out, int out_size, void* d_ws, size_t ws_size,
                              hipStream_t stream) {
  const float* Q  = (const float*)d_in[0];
  const float* K  = (const float*)d_in[1];
  const float* V  = (const float*)d_in[2];
  const float* R  = (const float*)d_in[3];
  const int*   Mk = (const int*)d_in[4];
  float* ans  = (float*)d_out;
  float* pout = ans + (size_t)4 * 8 * 512 * 64;  // p_attn after ans

  hipLaunchKernelGGL(attn_v4, dim3(1024), dim3(256), 0, stream,
                     Q, K, V, R, Mk, ans, pout);
}